// Round 1
// baseline (795.724 us; speedup 1.0000x reference)
//
#include <hip/hip_runtime.h>
#include <math.h>

#define BB 4
#define HH 512
#define WW 512
#define CC 32
#define PADC 3

struct Params {
    int ym, xm, hc, wc, rh, rw, dy, dx;
    float ry, rx;
};

__device__ __forceinline__ bool sig_bit(float v) {
    // matches round(sigmoid(v)) == 1 under round-half-even (0.5 exactly -> 0)
    return (1.0f / (1.0f + expf(-v))) > 0.5f;
}

// One block per (b,h) row: computes per-row channel mask (OR over w) and
// ORs per-(b,w) channel masks (OR over h) into colbits via atomics.
__global__ __launch_bounds__(256) void scan_kernel(const float* __restrict__ x,
                                                   unsigned int* __restrict__ rowbits,
                                                   unsigned int* __restrict__ colbits) {
    const int bh = blockIdx.x;          // b*HH + h
    const int b = bh >> 9;              // HH = 512
    const float* row = x + (size_t)bh * (WW * CC);
    const int t = threadIdx.x;
    const int lane = t & 63;
    unsigned int rowacc = 0;
    for (int k = t; k < WW * CC; k += 256) {
        float v = row[k];
        unsigned long long bal = __ballot(sig_bit(v));
        unsigned int m0 = (unsigned int)bal;          // c-mask for w = (k - lane) >> 5
        unsigned int m1 = (unsigned int)(bal >> 32);  // c-mask for that w + 1
        rowacc |= m0 | m1;
        if (lane == 0 && m0) atomicOr(&colbits[b * WW + (k >> 5)], m0);
        if (lane == 32 && m1) atomicOr(&colbits[b * WW + (k >> 5)], m1);
    }
    __shared__ unsigned int s[4];
    if (lane == 0) s[t >> 6] = rowacc;   // rowacc uniform per wave (ballot-derived)
    __syncthreads();
    if (t == 0) rowbits[bh] = s[0] | s[1] | s[2] | s[3];
}

// One wave per (b,c): first/last active index over cols and rows, then the
// resize arithmetic, exactly mirroring the reference (incl. argmax quirks).
__global__ __launch_bounds__(64) void bbox_kernel(const unsigned int* __restrict__ rowbits,
                                                  const unsigned int* __restrict__ colbits,
                                                  Params* __restrict__ prm) {
    const int bc = blockIdx.x;           // b*CC + c
    const int b = bc >> 5, c = bc & 31;
    const int lane = threadIdx.x;        // 0..63
    int fx = WW, lx = -1, fy = HH, ly = -1;
    const unsigned int* cb = colbits + b * WW;
    const unsigned int* rb = rowbits + b * HH;
    for (int m = 0; m < WW / 64; ++m) {
        int w = m * 64 + lane;
        if ((cb[w] >> c) & 1u) { fx = min(fx, w); lx = max(lx, w); }
        if ((rb[w] >> c) & 1u) { fy = min(fy, w); ly = max(ly, w); }
    }
    for (int off = 32; off; off >>= 1) {
        fx = min(fx, __shfl_xor(fx, off));
        lx = max(lx, __shfl_xor(lx, off));
        fy = min(fy, __shfl_xor(fy, off));
        ly = max(ly, __shfl_xor(ly, off));
    }
    if (lane == 0) {
        // argmax quirks: no active -> 0; for min-side, first active at last
        // index gives zero weight -> argmax returns 0.
        int xm = (fx <= WW - 2) ? fx : 0;
        int xM = (lx >= 0) ? lx : 0;
        int ym = (fy <= HH - 2) ? fy : 0;
        int yM = (ly >= 0) ? ly : 0;
        int hc = max(yM - ym, 1), wc = max(xM - xm, 1);
        int zh = max(HH - 2 * PADC, hc), zw = max(WW - 2 * PADC, wc);
        float scale = fminf((float)zh / (float)hc, (float)zw / (float)wc);
        int rh = (int)rintf(scale * (float)hc);   // round-half-even, matches jnp.round
        int rw = (int)rintf(scale * (float)wc);
        // max(0, floor-div) == max(0, C trunc-div) for these (negatives clamp to 0)
        int pad_y = max(0, (HH - rh) / 2), crop_y = max(0, (rh - HH) / 2);
        int pad_x = max(0, (WW - rw) / 2), crop_x = max(0, (rw - WW) / 2);
        Params p;
        p.ym = ym; p.xm = xm; p.hc = hc; p.wc = wc; p.rh = rh; p.rw = rw;
        p.dy = pad_y - crop_y; p.dx = pad_x - crop_x;
        p.ry = (float)hc / (float)rh;
        p.rx = (float)wc / (float)rw;
        prm[bc] = p;
    }
}

// One thread per output element, c fastest -> coalesced gathers per wave.
__global__ __launch_bounds__(256) void focus_kernel(const float* __restrict__ x,
                                                    const Params* __restrict__ prm,
                                                    float* __restrict__ out) {
    const int t = threadIdx.x;
    const size_t g = (size_t)blockIdx.x * 256 + t;
    const int c = (int)(g & 31);
    const int j = (int)((g >> 5) & 511);
    const int i = (int)((g >> 14) & 511);
    const int b = (int)(g >> 23);        // uniform per block

    __shared__ Params sp[CC];
    {
        const int nw = CC * (int)(sizeof(Params) / 4);
        const int* src = (const int*)(prm + b * CC);
        int* dst = (int*)sp;
        for (int k = t; k < nw; k += 256) dst[k] = src[k];
    }
    __syncthreads();
    Params p = sp[c];

    int ri = i - p.dy, rj = j - p.dx;
    bool valid = (ri >= 0) && (ri < p.rh) && (rj >= 0) && (rj < p.rw);
    float sy = (float)ri * p.ry;
    float sx = (float)rj * p.rx;
    int y0 = min(max((int)floorf(sy), 0), p.hc - 1);
    int x0 = min(max((int)floorf(sx), 0), p.wc - 1);
    int y1 = min(y0 + 1, p.hc - 1);
    int x1 = min(x0 + 1, p.wc - 1);
    float wy = fminf(fmaxf(sy - (float)y0, 0.0f), 1.0f);
    float wx = fminf(fmaxf(sx - (float)x0, 0.0f), 1.0f);
    int Y0 = min(p.ym + y0, HH - 1);
    int Y1 = min(p.ym + y1, HH - 1);
    int X0 = min(p.xm + x0, WW - 1);
    int X1 = min(p.xm + x1, WW - 1);

    const float* base = x + (size_t)b * ((size_t)HH * WW * CC);
    float v00 = base[((size_t)Y0 * WW + X0) * CC + c];
    float v01 = base[((size_t)Y0 * WW + X1) * CC + c];
    float v10 = base[((size_t)Y1 * WW + X0) * CC + c];
    float v11 = base[((size_t)Y1 * WW + X1) * CC + c];
    float top = v00 * (1.0f - wx) + v01 * wx;
    float bot = v10 * (1.0f - wx) + v11 * wx;
    float o = top * (1.0f - wy) + bot * wy;
    out[g] = valid ? o : 0.0f;
}

extern "C" void kernel_launch(void* const* d_in, const int* in_sizes, int n_in,
                              void* d_out, int out_size, void* d_ws, size_t ws_size,
                              hipStream_t stream) {
    const float* x = (const float*)d_in[0];
    float* out = (float*)d_out;
    unsigned char* ws = (unsigned char*)d_ws;
    unsigned int* colbits = (unsigned int*)ws;            // BB*WW words = 8 KiB
    unsigned int* rowbits = (unsigned int*)(ws + 8192);   // BB*HH words = 8 KiB
    Params* prm = (Params*)(ws + 16384);                  // 128 * 40 B

    hipMemsetAsync(d_ws, 0, 16384, stream);               // zero bitmasks every call
    hipLaunchKernelGGL(scan_kernel, dim3(BB * HH), dim3(256), 0, stream,
                       x, rowbits, colbits);
    hipLaunchKernelGGL(bbox_kernel, dim3(BB * CC), dim3(64), 0, stream,
                       rowbits, colbits, prm);
    hipLaunchKernelGGL(focus_kernel, dim3((BB * HH * WW * CC) / 256), dim3(256), 0, stream,
                       x, prm, out);
}

// Round 2
// 138.828 us; speedup vs baseline: 5.7317x; 5.7317x over previous
//
#include <hip/hip_runtime.h>
#include <math.h>

#define BB 4
#define HH 512
#define WW 512
#define CC 32
#define PADC 3

struct Params {
    int ym, xm, hc, wc, rh, rw, dy, dx;
    float ry, rx;
};

__device__ __forceinline__ bool sig_bit(float v) {
    // matches round(sigmoid(v)) == 1 under round-half-even (0.5 exactly -> 0)
    return (1.0f / (1.0f + expf(-v))) > 0.5f;
}

// One block per (b,h) row. float4 loads; 8-lane shuffle-OR assembles the
// 32-bit channel mask for each w; one plain store per w into wmask (no
// contended atomics). Row mask reduced in-wave -> rowbits[bh].
__global__ __launch_bounds__(256) void scan_kernel(const float* __restrict__ x,
                                                   unsigned int* __restrict__ rowbits,
                                                   unsigned int* __restrict__ wmask) {
    const int bh = blockIdx.x;                 // b*HH + h
    const float4* row = (const float4*)(x + (size_t)bh * (WW * CC));
    unsigned int* wrow = wmask + (size_t)bh * WW;
    const int t = threadIdx.x;
    unsigned int rowacc = 0;
    // 512*32 floats = 4096 float4; 256 threads -> 16 iters
    #pragma unroll 4
    for (int it = 0; it < 16; ++it) {
        int idx = it * 256 + t;                // float4 index; elements 4*idx..+3
        float4 v = row[idx];
        unsigned int nib = (sig_bit(v.x) ? 1u : 0u) | (sig_bit(v.y) ? 2u : 0u) |
                           (sig_bit(v.z) ? 4u : 0u) | (sig_bit(v.w) ? 8u : 0u);
        // c = 4*(t&7)+e within this w; 8 consecutive lanes cover one w
        unsigned int m = nib << ((t & 7) * 4);
        m |= __shfl_xor(m, 1);
        m |= __shfl_xor(m, 2);
        m |= __shfl_xor(m, 4);                 // m = c-mask for w = idx>>3, uniform in 8-group
        rowacc |= m;
        if ((t & 7) == 0) wrow[idx >> 3] = m;
    }
    // OR across the eight 8-lane groups of the wave
    rowacc |= __shfl_xor(rowacc, 8);
    rowacc |= __shfl_xor(rowacc, 16);
    rowacc |= __shfl_xor(rowacc, 32);
    __shared__ unsigned int s[4];
    if ((t & 63) == 0) s[t >> 6] = rowacc;
    __syncthreads();
    if (t == 0) rowbits[bh] = s[0] | s[1] | s[2] | s[3];
}

// OR wmask over h -> colbits[b][w]. 8 h-chunks per (b,w): <=8 atomics/address.
__global__ __launch_bounds__(256) void colreduce_kernel(const unsigned int* __restrict__ wmask,
                                                        unsigned int* __restrict__ colbits) {
    const int blk = blockIdx.x;                // b(2b) | wchunk(1b) | hchunk(3b)
    const int b = blk >> 4;
    const int w = ((blk >> 3) & 1) * 256 + threadIdx.x;
    const int h0 = (blk & 7) * 64;
    const unsigned int* base = wmask + ((size_t)b * HH + h0) * WW + w;
    unsigned int acc = 0;
    #pragma unroll 8
    for (int h = 0; h < 64; ++h) acc |= base[(size_t)h * WW];
    if (acc) atomicOr(&colbits[b * WW + w], acc);
}

// One wave per (b,c): first/last active index over cols and rows, then the
// resize arithmetic, exactly mirroring the reference (incl. argmax quirks).
__global__ __launch_bounds__(64) void bbox_kernel(const unsigned int* __restrict__ rowbits,
                                                  const unsigned int* __restrict__ colbits,
                                                  Params* __restrict__ prm) {
    const int bc = blockIdx.x;           // b*CC + c
    const int b = bc >> 5, c = bc & 31;
    const int lane = threadIdx.x;        // 0..63
    int fx = WW, lx = -1, fy = HH, ly = -1;
    const unsigned int* cb = colbits + b * WW;
    const unsigned int* rb = rowbits + b * HH;
    for (int m = 0; m < WW / 64; ++m) {
        int w = m * 64 + lane;
        if ((cb[w] >> c) & 1u) { fx = min(fx, w); lx = max(lx, w); }
        if ((rb[w] >> c) & 1u) { fy = min(fy, w); ly = max(ly, w); }
    }
    for (int off = 32; off; off >>= 1) {
        fx = min(fx, __shfl_xor(fx, off));
        lx = max(lx, __shfl_xor(lx, off));
        fy = min(fy, __shfl_xor(fy, off));
        ly = max(ly, __shfl_xor(ly, off));
    }
    if (lane == 0) {
        // argmax quirks: no active -> 0; for min-side, first active at last
        // index gives zero weight -> argmax returns 0.
        int xm = (fx <= WW - 2) ? fx : 0;
        int xM = (lx >= 0) ? lx : 0;
        int ym = (fy <= HH - 2) ? fy : 0;
        int yM = (ly >= 0) ? ly : 0;
        int hc = max(yM - ym, 1), wc = max(xM - xm, 1);
        int zh = max(HH - 2 * PADC, hc), zw = max(WW - 2 * PADC, wc);
        float scale = fminf((float)zh / (float)hc, (float)zw / (float)wc);
        int rh = (int)rintf(scale * (float)hc);   // round-half-even, matches jnp.round
        int rw = (int)rintf(scale * (float)wc);
        // max(0, floor-div) == max(0, C trunc-div) for these (negatives clamp to 0)
        int pad_y = max(0, (HH - rh) / 2), crop_y = max(0, (rh - HH) / 2);
        int pad_x = max(0, (WW - rw) / 2), crop_x = max(0, (rw - WW) / 2);
        Params p;
        p.ym = ym; p.xm = xm; p.hc = hc; p.wc = wc; p.rh = rh; p.rw = rw;
        p.dy = pad_y - crop_y; p.dx = pad_x - crop_x;
        p.ry = (float)hc / (float)rh;
        p.rx = (float)wc / (float)rw;
        prm[bc] = p;
    }
}

// One thread per output element, c fastest -> coalesced gathers per wave.
__global__ __launch_bounds__(256) void focus_kernel(const float* __restrict__ x,
                                                    const Params* __restrict__ prm,
                                                    float* __restrict__ out) {
    const int t = threadIdx.x;
    const size_t g = (size_t)blockIdx.x * 256 + t;
    const int c = (int)(g & 31);
    const int j = (int)((g >> 5) & 511);
    const int i = (int)((g >> 14) & 511);
    const int b = (int)(g >> 23);        // uniform per block

    __shared__ Params sp[CC];
    {
        const int nw = CC * (int)(sizeof(Params) / 4);
        const int* src = (const int*)(prm + b * CC);
        int* dst = (int*)sp;
        for (int k = t; k < nw; k += 256) dst[k] = src[k];
    }
    __syncthreads();
    Params p = sp[c];

    int ri = i - p.dy, rj = j - p.dx;
    bool valid = (ri >= 0) && (ri < p.rh) && (rj >= 0) && (rj < p.rw);
    float sy = (float)ri * p.ry;
    float sx = (float)rj * p.rx;
    int y0 = min(max((int)floorf(sy), 0), p.hc - 1);
    int x0 = min(max((int)floorf(sx), 0), p.wc - 1);
    int y1 = min(y0 + 1, p.hc - 1);
    int x1 = min(x0 + 1, p.wc - 1);
    float wy = fminf(fmaxf(sy - (float)y0, 0.0f), 1.0f);
    float wx = fminf(fmaxf(sx - (float)x0, 0.0f), 1.0f);
    int Y0 = min(p.ym + y0, HH - 1);
    int Y1 = min(p.ym + y1, HH - 1);
    int X0 = min(p.xm + x0, WW - 1);
    int X1 = min(p.xm + x1, WW - 1);

    const float* base = x + (size_t)b * ((size_t)HH * WW * CC);
    float v00 = base[((size_t)Y0 * WW + X0) * CC + c];
    float v01 = base[((size_t)Y0 * WW + X1) * CC + c];
    float v10 = base[((size_t)Y1 * WW + X0) * CC + c];
    float v11 = base[((size_t)Y1 * WW + X1) * CC + c];
    float top = v00 * (1.0f - wx) + v01 * wx;
    float bot = v10 * (1.0f - wx) + v11 * wx;
    float o = top * (1.0f - wy) + bot * wy;
    out[g] = valid ? o : 0.0f;
}

extern "C" void kernel_launch(void* const* d_in, const int* in_sizes, int n_in,
                              void* d_out, int out_size, void* d_ws, size_t ws_size,
                              hipStream_t stream) {
    const float* x = (const float*)d_in[0];
    float* out = (float*)d_out;
    unsigned char* ws = (unsigned char*)d_ws;
    unsigned int* colbits = (unsigned int*)ws;            // BB*WW words = 8 KiB
    unsigned int* rowbits = (unsigned int*)(ws + 8192);   // BB*HH words = 8 KiB
    Params* prm = (Params*)(ws + 16384);                  // 128 * 40 B

    const size_t wmask_bytes = (size_t)BB * HH * WW * 4;  // 4 MiB
    unsigned int* wmask = (ws_size >= 32768 + wmask_bytes)
                              ? (unsigned int*)(ws + 32768)
                              : (unsigned int*)d_out;     // scratch; focus overwrites

    hipMemsetAsync(colbits, 0, BB * WW * 4, stream);      // only colbits needs zeroing
    hipLaunchKernelGGL(scan_kernel, dim3(BB * HH), dim3(256), 0, stream,
                       x, rowbits, wmask);
    hipLaunchKernelGGL(colreduce_kernel, dim3(BB * 2 * 8), dim3(256), 0, stream,
                       wmask, colbits);
    hipLaunchKernelGGL(bbox_kernel, dim3(BB * CC), dim3(64), 0, stream,
                       rowbits, colbits, prm);
    hipLaunchKernelGGL(focus_kernel, dim3((BB * HH * WW * CC) / 256), dim3(256), 0, stream,
                       x, prm, out);
}

// Round 3
// 84.441 us; speedup vs baseline: 9.4234x; 1.6441x over previous
//
#include <hip/hip_runtime.h>
#include <math.h>

#define BB 4
#define HH 512
#define WW 512
#define CC 32
#define PADC 3

struct Params {
    int ym, xm, hc, wc, rh, rw, dy, dx;
    float ry, rx;
};

struct FastRec {
    int flag, iLo, iHi, jLo, jHi, dY, dX, pad;
};

__device__ __forceinline__ bool sig_bit(float v) {
    // matches round(sigmoid(v)) == 1 under round-half-even (0.5 exactly -> 0)
    return (1.0f / (1.0f + expf(-v))) > 0.5f;
}

// One block per (b,h) row. float4 loads; 8-lane shuffle-OR assembles the
// 32-bit channel mask for each w; one plain store per w into wmask (no
// contended atomics). Row mask reduced in-wave -> rowbits[bh].
__global__ __launch_bounds__(256) void scan_kernel(const float* __restrict__ x,
                                                   unsigned int* __restrict__ rowbits,
                                                   unsigned int* __restrict__ wmask) {
    const int bh = blockIdx.x;                 // b*HH + h
    const float4* row = (const float4*)(x + (size_t)bh * (WW * CC));
    unsigned int* wrow = wmask + (size_t)bh * WW;
    const int t = threadIdx.x;
    unsigned int rowacc = 0;
    // 512*32 floats = 4096 float4; 256 threads -> 16 iters
    #pragma unroll 4
    for (int it = 0; it < 16; ++it) {
        int idx = it * 256 + t;                // float4 index; elements 4*idx..+3
        float4 v = row[idx];
        unsigned int nib = (sig_bit(v.x) ? 1u : 0u) | (sig_bit(v.y) ? 2u : 0u) |
                           (sig_bit(v.z) ? 4u : 0u) | (sig_bit(v.w) ? 8u : 0u);
        // c = 4*(t&7)+e within this w; 8 consecutive lanes cover one w
        unsigned int m = nib << ((t & 7) * 4);
        m |= __shfl_xor(m, 1);
        m |= __shfl_xor(m, 2);
        m |= __shfl_xor(m, 4);                 // m = c-mask for w = idx>>3, uniform in 8-group
        rowacc |= m;
        if ((t & 7) == 0) wrow[idx >> 3] = m;
    }
    // OR across the eight 8-lane groups of the wave
    rowacc |= __shfl_xor(rowacc, 8);
    rowacc |= __shfl_xor(rowacc, 16);
    rowacc |= __shfl_xor(rowacc, 32);
    __shared__ unsigned int s[4];
    if ((t & 63) == 0) s[t >> 6] = rowacc;
    __syncthreads();
    if (t == 0) rowbits[bh] = s[0] | s[1] | s[2] | s[3];
}

// OR wmask over h -> colbits[b][w]. 8 h-chunks per (b,w): <=8 atomics/address.
__global__ __launch_bounds__(256) void colreduce_kernel(const unsigned int* __restrict__ wmask,
                                                        unsigned int* __restrict__ colbits) {
    const int blk = blockIdx.x;                // b(2b) | wchunk(1b) | hchunk(3b)
    const int b = blk >> 4;
    const int w = ((blk >> 3) & 1) * 256 + threadIdx.x;
    const int h0 = (blk & 7) * 64;
    const unsigned int* base = wmask + ((size_t)b * HH + h0) * WW + w;
    unsigned int acc = 0;
    #pragma unroll 8
    for (int h = 0; h < 64; ++h) acc |= base[(size_t)h * WW];
    if (acc) atomicOr(&colbits[b * WW + w], acc);
}

// One wave per (b,c): first/last active index over cols and rows, then the
// resize arithmetic, exactly mirroring the reference (incl. argmax quirks).
__global__ __launch_bounds__(64) void bbox_kernel(const unsigned int* __restrict__ rowbits,
                                                  const unsigned int* __restrict__ colbits,
                                                  Params* __restrict__ prm) {
    const int bc = blockIdx.x;           // b*CC + c
    const int b = bc >> 5, c = bc & 31;
    const int lane = threadIdx.x;        // 0..63
    int fx = WW, lx = -1, fy = HH, ly = -1;
    const unsigned int* cb = colbits + b * WW;
    const unsigned int* rb = rowbits + b * HH;
    for (int m = 0; m < WW / 64; ++m) {
        int w = m * 64 + lane;
        if ((cb[w] >> c) & 1u) { fx = min(fx, w); lx = max(lx, w); }
        if ((rb[w] >> c) & 1u) { fy = min(fy, w); ly = max(ly, w); }
    }
    for (int off = 32; off; off >>= 1) {
        fx = min(fx, __shfl_xor(fx, off));
        lx = max(lx, __shfl_xor(lx, off));
        fy = min(fy, __shfl_xor(fy, off));
        ly = max(ly, __shfl_xor(ly, off));
    }
    if (lane == 0) {
        // argmax quirks: no active -> 0; for min-side, first active at last
        // index gives zero weight -> argmax returns 0.
        int xm = (fx <= WW - 2) ? fx : 0;
        int xM = (lx >= 0) ? lx : 0;
        int ym = (fy <= HH - 2) ? fy : 0;
        int yM = (ly >= 0) ? ly : 0;
        int hc = max(yM - ym, 1), wc = max(xM - xm, 1);
        int zh = max(HH - 2 * PADC, hc), zw = max(WW - 2 * PADC, wc);
        float scale = fminf((float)zh / (float)hc, (float)zw / (float)wc);
        int rh = (int)rintf(scale * (float)hc);   // round-half-even, matches jnp.round
        int rw = (int)rintf(scale * (float)wc);
        // max(0, floor-div) == max(0, C trunc-div) for these (negatives clamp to 0)
        int pad_y = max(0, (HH - rh) / 2), crop_y = max(0, (rh - HH) / 2);
        int pad_x = max(0, (WW - rw) / 2), crop_x = max(0, (rw - WW) / 2);
        Params p;
        p.ym = ym; p.xm = xm; p.hc = hc; p.wc = wc; p.rh = rh; p.rw = rw;
        p.dy = pad_y - crop_y; p.dx = pad_x - crop_x;
        p.ry = (float)hc / (float)rh;
        p.rx = (float)wc / (float)rw;
        prm[bc] = p;
    }
}

// Per-b fast-path detection: all channels "simple" (rh==hc && rw==wc =>
// exact 1.0 scale => wy==wx==0 => pure shifted copy) with identical params.
__global__ __launch_bounds__(128) void finalize_kernel(const Params* __restrict__ prm,
                                                       FastRec* __restrict__ fast) {
    __shared__ Params sp[BB * CC];
    __shared__ int ok[BB * CC];
    const int t = threadIdx.x;           // 0..127 = b*32+c
    sp[t] = prm[t];
    __syncthreads();
    const int b = t >> 5, c = t & 31;
    Params p = sp[t];
    const Params& p0 = sp[b * CC];
    bool simple = (p.rh == p.hc) && (p.rw == p.wc);
    bool same = (p.ym == p0.ym) && (p.xm == p0.xm) && (p.dy == p0.dy) &&
                (p.dx == p0.dx) && (p.rh == p0.rh) && (p.rw == p0.rw);
    ok[t] = (simple && same) ? 1 : 0;
    __syncthreads();
    if (c == 0) {
        int all = 1;
        for (int k = 0; k < CC; ++k) all &= ok[b * CC + k];
        FastRec f;
        f.flag = all;
        f.iLo = p0.dy; f.iHi = p0.dy + p0.rh;
        f.jLo = p0.dx; f.jHi = p0.dx + p0.rw;
        f.dY = p0.ym - p0.dy; f.dX = p0.xm - p0.dx;
        f.pad = 0;
        fast[b] = f;
    }
}

// One float4 (4 channels of one (b,i,j)) per thread. Fast path: shifted
// coalesced copy. Slow path: per-channel bilinear (general case).
__global__ __launch_bounds__(256) void focus_kernel(const float* __restrict__ x,
                                                    const Params* __restrict__ prm,
                                                    const FastRec* __restrict__ fast,
                                                    float* __restrict__ out) {
    const int t = threadIdx.x;
    const size_t q = (size_t)blockIdx.x * 256 + t;   // float4 index
    const int c0 = (int)(q & 7) * 4;                 // 8 float4 per (i,j)
    const int j = (int)((q >> 3) & 511);
    const int i = (int)((q >> 12) & 511);
    const int b = (int)(q >> 21);                    // uniform per block

    FastRec f = fast[b];
    if (f.flag) {                                    // block-uniform branch
        float4 v = make_float4(0.f, 0.f, 0.f, 0.f);
        if (i >= f.iLo && i < f.iHi && j >= f.jLo && j < f.jHi) {
            const float* src = x + ((size_t)b * HH + (i + f.dY)) * ((size_t)WW * CC) +
                               (size_t)(j + f.dX) * CC + c0;
            v = *(const float4*)src;
        }
        ((float4*)out)[q] = v;
        return;
    }

    __shared__ Params sp[CC];
    {
        const int nw = CC * (int)(sizeof(Params) / 4);
        const int* src = (const int*)(prm + b * CC);
        int* dst = (int*)sp;
        for (int k = t; k < nw; k += 256) dst[k] = src[k];
    }
    __syncthreads();

    const float* base = x + (size_t)b * ((size_t)HH * WW * CC);
    float r[4];
    #pragma unroll
    for (int k = 0; k < 4; ++k) {
        Params p = sp[c0 + k];
        int ri = i - p.dy, rj = j - p.dx;
        bool valid = (ri >= 0) && (ri < p.rh) && (rj >= 0) && (rj < p.rw);
        float sy = (float)ri * p.ry;
        float sx = (float)rj * p.rx;
        int y0 = min(max((int)floorf(sy), 0), p.hc - 1);
        int x0 = min(max((int)floorf(sx), 0), p.wc - 1);
        int y1 = min(y0 + 1, p.hc - 1);
        int x1 = min(x0 + 1, p.wc - 1);
        float wy = fminf(fmaxf(sy - (float)y0, 0.0f), 1.0f);
        float wx = fminf(fmaxf(sx - (float)x0, 0.0f), 1.0f);
        int Y0 = min(p.ym + y0, HH - 1);
        int Y1 = min(p.ym + y1, HH - 1);
        int X0 = min(p.xm + x0, WW - 1);
        int X1 = min(p.xm + x1, WW - 1);
        float v00 = base[((size_t)Y0 * WW + X0) * CC + c0 + k];
        float v01 = base[((size_t)Y0 * WW + X1) * CC + c0 + k];
        float v10 = base[((size_t)Y1 * WW + X0) * CC + c0 + k];
        float v11 = base[((size_t)Y1 * WW + X1) * CC + c0 + k];
        float top = v00 * (1.0f - wx) + v01 * wx;
        float bot = v10 * (1.0f - wx) + v11 * wx;
        float o = top * (1.0f - wy) + bot * wy;
        r[k] = valid ? o : 0.0f;
    }
    ((float4*)out)[q] = make_float4(r[0], r[1], r[2], r[3]);
}

extern "C" void kernel_launch(void* const* d_in, const int* in_sizes, int n_in,
                              void* d_out, int out_size, void* d_ws, size_t ws_size,
                              hipStream_t stream) {
    const float* x = (const float*)d_in[0];
    float* out = (float*)d_out;
    unsigned char* ws = (unsigned char*)d_ws;
    unsigned int* colbits = (unsigned int*)ws;            // BB*WW words = 8 KiB
    unsigned int* rowbits = (unsigned int*)(ws + 8192);   // BB*HH words = 8 KiB
    Params* prm = (Params*)(ws + 16384);                  // 128 * 40 B
    FastRec* fast = (FastRec*)(ws + 24576);               // 4 * 32 B

    const size_t wmask_bytes = (size_t)BB * HH * WW * 4;  // 4 MiB
    unsigned int* wmask = (ws_size >= 32768 + wmask_bytes)
                              ? (unsigned int*)(ws + 32768)
                              : (unsigned int*)d_out;     // scratch; focus overwrites

    hipMemsetAsync(colbits, 0, BB * WW * 4, stream);      // only colbits needs zeroing
    hipLaunchKernelGGL(scan_kernel, dim3(BB * HH), dim3(256), 0, stream,
                       x, rowbits, wmask);
    hipLaunchKernelGGL(colreduce_kernel, dim3(BB * 2 * 8), dim3(256), 0, stream,
                       wmask, colbits);
    hipLaunchKernelGGL(bbox_kernel, dim3(BB * CC), dim3(64), 0, stream,
                       rowbits, colbits, prm);
    hipLaunchKernelGGL(finalize_kernel, dim3(1), dim3(128), 0, stream, prm, fast);
    hipLaunchKernelGGL(focus_kernel, dim3((BB * HH * WW * CC / 4) / 256), dim3(256), 0, stream,
                       x, prm, fast, out);
}

// Round 5
// 83.192 us; speedup vs baseline: 9.5649x; 1.0150x over previous
//
#include <hip/hip_runtime.h>
#include <math.h>

#define BB 4
#define HH 512
#define WW 512
#define CC 32
#define PADC 3

typedef float f4nat __attribute__((ext_vector_type(4)));  // NT-store-compatible

struct Params {
    int ym, xm, hc, wc, rh, rw, dy, dx;
    float ry, rx;
};

struct FastRec {
    int flag, iLo, iHi, jLo, jHi, dY, dX, pad;
};

__device__ __forceinline__ bool sig_bit(float v) {
    // matches round(sigmoid(v)) == 1 under round-half-even (0.5 exactly -> 0)
    return (1.0f / (1.0f + expf(-v))) > 0.5f;
}

// One block per (b,h) row. float4 loads; 8-lane shuffle-OR assembles the
// 32-bit channel mask for each w; one plain store per w into wmask (no
// contended atomics). Row mask reduced in-wave -> rowbits[bh].
__global__ __launch_bounds__(256) void scan_kernel(const float* __restrict__ x,
                                                   unsigned int* __restrict__ rowbits,
                                                   unsigned int* __restrict__ wmask) {
    const int bh = blockIdx.x;                 // b*HH + h
    const float4* row = (const float4*)(x + (size_t)bh * (WW * CC));
    unsigned int* wrow = wmask + (size_t)bh * WW;
    const int t = threadIdx.x;
    unsigned int rowacc = 0;
    // 512*32 floats = 4096 float4; 256 threads -> 16 iters
    #pragma unroll 4
    for (int it = 0; it < 16; ++it) {
        int idx = it * 256 + t;                // float4 index; elements 4*idx..+3
        float4 v = row[idx];
        unsigned int nib = (sig_bit(v.x) ? 1u : 0u) | (sig_bit(v.y) ? 2u : 0u) |
                           (sig_bit(v.z) ? 4u : 0u) | (sig_bit(v.w) ? 8u : 0u);
        // c = 4*(t&7)+e within this w; 8 consecutive lanes cover one w
        unsigned int m = nib << ((t & 7) * 4);
        m |= __shfl_xor(m, 1);
        m |= __shfl_xor(m, 2);
        m |= __shfl_xor(m, 4);                 // m = c-mask for w = idx>>3, uniform in 8-group
        rowacc |= m;
        if ((t & 7) == 0) wrow[idx >> 3] = m;
    }
    // OR across the eight 8-lane groups of the wave
    rowacc |= __shfl_xor(rowacc, 8);
    rowacc |= __shfl_xor(rowacc, 16);
    rowacc |= __shfl_xor(rowacc, 32);
    __shared__ unsigned int s[4];
    if ((t & 63) == 0) s[t >> 6] = rowacc;
    __syncthreads();
    if (t == 0) rowbits[bh] = s[0] | s[1] | s[2] | s[3];
}

// OR wmask over a 64-h chunk -> colpart[hchunk][b][w]. Plain stores, no
// atomics, no pre-zeroing needed (every word is written).
__global__ __launch_bounds__(256) void colreduce_kernel(const unsigned int* __restrict__ wmask,
                                                        unsigned int* __restrict__ colpart) {
    const int blk = blockIdx.x;                // b(2b) | wchunk(1b) | hchunk(3b)
    const int b = blk >> 4;
    const int w = ((blk >> 3) & 1) * 256 + threadIdx.x;
    const int hk = blk & 7;
    const unsigned int* base = wmask + ((size_t)b * HH + hk * 64) * WW + w;
    unsigned int acc = 0;
    #pragma unroll 8
    for (int h = 0; h < 64; ++h) acc |= base[(size_t)h * WW];
    colpart[((size_t)hk * BB + b) * WW + w] = acc;
}

// One block per b (1024 threads = 32 lanes per channel). Scans rowbits +
// the 8 colpart chunks, computes Params per (b,c) (same arithmetic as the
// reference incl. argmax quirks), then the per-b fast-path record.
__global__ __launch_bounds__(1024) void bboxfin_kernel(const unsigned int* __restrict__ rowbits,
                                                       const unsigned int* __restrict__ colpart,
                                                       Params* __restrict__ prm,
                                                       FastRec* __restrict__ fast) {
    const int b = blockIdx.x;
    const int t = threadIdx.x;
    const int c = t >> 5;                // 0..31
    const int lane = t & 31;
    int fx = WW, lx = -1, fy = HH, ly = -1;
    const unsigned int* rb = rowbits + b * HH;
    for (int m = 0; m < WW / 32; ++m) {  // 16 iters
        int w = m * 32 + lane;
        unsigned int cm = 0;
        #pragma unroll
        for (int k = 0; k < 8; ++k) cm |= colpart[((size_t)k * BB + b) * WW + w];
        if ((cm >> c) & 1u) { fx = min(fx, w); lx = max(lx, w); }
        if ((rb[w] >> c) & 1u) { fy = min(fy, w); ly = max(ly, w); }
    }
    // reduce within the 32-lane group (offsets <=16 stay inside the group)
    for (int off = 16; off; off >>= 1) {
        fx = min(fx, __shfl_xor(fx, off));
        lx = max(lx, __shfl_xor(lx, off));
        fy = min(fy, __shfl_xor(fy, off));
        ly = max(ly, __shfl_xor(ly, off));
    }
    __shared__ Params sp[CC];
    __shared__ int ok[CC];
    if (lane == 0) {
        // argmax quirks: no active -> 0; for min-side, first active at last
        // index gives zero weight -> argmax returns 0.
        int xm = (fx <= WW - 2) ? fx : 0;
        int xM = (lx >= 0) ? lx : 0;
        int ym = (fy <= HH - 2) ? fy : 0;
        int yM = (ly >= 0) ? ly : 0;
        int hc = max(yM - ym, 1), wc = max(xM - xm, 1);
        int zh = max(HH - 2 * PADC, hc), zw = max(WW - 2 * PADC, wc);
        float scale = fminf((float)zh / (float)hc, (float)zw / (float)wc);
        int rh = (int)rintf(scale * (float)hc);   // round-half-even, matches jnp.round
        int rw = (int)rintf(scale * (float)wc);
        // max(0, floor-div) == max(0, C trunc-div) for these (negatives clamp to 0)
        int pad_y = max(0, (HH - rh) / 2), crop_y = max(0, (rh - HH) / 2);
        int pad_x = max(0, (WW - rw) / 2), crop_x = max(0, (rw - WW) / 2);
        Params p;
        p.ym = ym; p.xm = xm; p.hc = hc; p.wc = wc; p.rh = rh; p.rw = rw;
        p.dy = pad_y - crop_y; p.dx = pad_x - crop_x;
        p.ry = (float)hc / (float)rh;
        p.rx = (float)wc / (float)rw;
        sp[c] = p;
    }
    __syncthreads();
    if (t < CC) {
        Params p = sp[t];
        const Params& p0 = sp[0];
        bool simple = (p.rh == p.hc) && (p.rw == p.wc);   // => scale ratio exactly 1
        bool same = (p.ym == p0.ym) && (p.xm == p0.xm) && (p.dy == p0.dy) &&
                    (p.dx == p0.dx) && (p.rh == p0.rh) && (p.rw == p0.rw);
        ok[t] = (simple && same) ? 1 : 0;
        prm[b * CC + t] = p;
    }
    __syncthreads();
    if (t == 0) {
        int all = 1;
        for (int k = 0; k < CC; ++k) all &= ok[k];
        Params p0 = sp[0];
        FastRec f;
        f.flag = all;
        f.iLo = p0.dy; f.iHi = p0.dy + p0.rh;
        f.jLo = p0.dx; f.jHi = p0.dx + p0.rw;
        f.dY = p0.ym - p0.dy; f.dX = p0.xm - p0.dx;
        f.pad = 0;
        fast[b] = f;
    }
}

// One float4 (4 channels of one (b,i,j)) per thread. Fast path: shifted
// coalesced copy. Slow path: per-channel bilinear (general case). Output
// stores are non-temporal so the 134 MB write stream doesn't evict the
// input from L3 (keeps scan+focus reads L3-resident across replays).
__global__ __launch_bounds__(256) void focus_kernel(const float* __restrict__ x,
                                                    const Params* __restrict__ prm,
                                                    const FastRec* __restrict__ fast,
                                                    float* __restrict__ out) {
    const int t = threadIdx.x;
    const size_t q = (size_t)blockIdx.x * 256 + t;   // float4 index
    const int c0 = (int)(q & 7) * 4;                 // 8 float4 per (i,j)
    const int j = (int)((q >> 3) & 511);
    const int i = (int)((q >> 12) & 511);
    const int b = (int)(q >> 21);                    // uniform per block

    FastRec f = fast[b];
    if (f.flag) {                                    // block-uniform branch
        f4nat v = (f4nat)0.0f;
        if (i >= f.iLo && i < f.iHi && j >= f.jLo && j < f.jHi) {
            const float* src = x + ((size_t)b * HH + (i + f.dY)) * ((size_t)WW * CC) +
                               (size_t)(j + f.dX) * CC + c0;
            v = *(const f4nat*)src;
        }
        __builtin_nontemporal_store(v, (f4nat*)out + q);
        return;
    }

    __shared__ Params sp[CC];
    {
        const int nw = CC * (int)(sizeof(Params) / 4);
        const int* src = (const int*)(prm + b * CC);
        int* dst = (int*)sp;
        for (int k = t; k < nw; k += 256) dst[k] = src[k];
    }
    __syncthreads();

    const float* base = x + (size_t)b * ((size_t)HH * WW * CC);
    f4nat r;
    #pragma unroll
    for (int k = 0; k < 4; ++k) {
        Params p = sp[c0 + k];
        int ri = i - p.dy, rj = j - p.dx;
        bool valid = (ri >= 0) && (ri < p.rh) && (rj >= 0) && (rj < p.rw);
        float sy = (float)ri * p.ry;
        float sx = (float)rj * p.rx;
        int y0 = min(max((int)floorf(sy), 0), p.hc - 1);
        int x0 = min(max((int)floorf(sx), 0), p.wc - 1);
        int y1 = min(y0 + 1, p.hc - 1);
        int x1 = min(x0 + 1, p.wc - 1);
        float wy = fminf(fmaxf(sy - (float)y0, 0.0f), 1.0f);
        float wx = fminf(fmaxf(sx - (float)x0, 0.0f), 1.0f);
        int Y0 = min(p.ym + y0, HH - 1);
        int Y1 = min(p.ym + y1, HH - 1);
        int X0 = min(p.xm + x0, WW - 1);
        int X1 = min(p.xm + x1, WW - 1);
        float v00 = base[((size_t)Y0 * WW + X0) * CC + c0 + k];
        float v01 = base[((size_t)Y0 * WW + X1) * CC + c0 + k];
        float v10 = base[((size_t)Y1 * WW + X0) * CC + c0 + k];
        float v11 = base[((size_t)Y1 * WW + X1) * CC + c0 + k];
        float top = v00 * (1.0f - wx) + v01 * wx;
        float bot = v10 * (1.0f - wx) + v11 * wx;
        float o = top * (1.0f - wy) + bot * wy;
        r[k] = valid ? o : 0.0f;
    }
    __builtin_nontemporal_store(r, (f4nat*)out + q);
}

extern "C" void kernel_launch(void* const* d_in, const int* in_sizes, int n_in,
                              void* d_out, int out_size, void* d_ws, size_t ws_size,
                              hipStream_t stream) {
    const float* x = (const float*)d_in[0];
    float* out = (float*)d_out;
    unsigned char* ws = (unsigned char*)d_ws;
    unsigned int* colpart = (unsigned int*)ws;                 // 8*BB*WW words = 64 KiB
    unsigned int* rowbits = (unsigned int*)(ws + 65536);       // BB*HH words = 8 KiB
    Params* prm = (Params*)(ws + 73728);                       // 128 * 40 B
    FastRec* fast = (FastRec*)(ws + 78848);                    // 4 * 32 B

    const size_t wmask_off = 81920;
    const size_t wmask_bytes = (size_t)BB * HH * WW * 4;       // 4 MiB
    unsigned int* wmask = (ws_size >= wmask_off + wmask_bytes)
                              ? (unsigned int*)(ws + wmask_off)
                              : (unsigned int*)d_out;          // scratch; focus overwrites

    hipLaunchKernelGGL(scan_kernel, dim3(BB * HH), dim3(256), 0, stream,
                       x, rowbits, wmask);
    hipLaunchKernelGGL(colreduce_kernel, dim3(BB * 2 * 8), dim3(256), 0, stream,
                       wmask, colpart);
    hipLaunchKernelGGL(bboxfin_kernel, dim3(BB), dim3(1024), 0, stream,
                       rowbits, colpart, prm, fast);
    hipLaunchKernelGGL(focus_kernel, dim3((BB * HH * WW * CC / 4) / 256), dim3(256), 0, stream,
                       x, prm, fast, out);
}

// Round 6
// 57.625 us; speedup vs baseline: 13.8087x; 1.4437x over previous
//
#include <hip/hip_runtime.h>
#include <math.h>

#define BB 4
#define HH 512
#define WW 512
#define CC 32
#define PADC 3

typedef float f4nat __attribute__((ext_vector_type(4)));  // NT-store-compatible

struct Params {
    int ym, xm, hc, wc, rh, rw, dy, dx;
    float ry, rx;
};

struct FastRec {
    int flag, iLo, iHi, jLo, jHi, dY, dX, pad;
};

__device__ __forceinline__ bool sig_bit(float v) {
    // matches round(sigmoid(v)) == 1 under round-half-even (0.5 exactly -> 0)
    return (1.0f / (1.0f + expf(-v))) > 0.5f;
}

// One block per (b,h) row. f4 loads; 8-lane shuffle-OR assembles the 32-bit
// channel mask per w -> wmask (plain stores). Row mask -> rowbits. When
// doCopy!=0 also streams the row verbatim to out (NT store): speculative
// identity copy, corrected afterwards by fixup_kernel.
__global__ __launch_bounds__(256) void scan_kernel(const float* __restrict__ x,
                                                   unsigned int* __restrict__ rowbits,
                                                   unsigned int* __restrict__ wmask,
                                                   float* __restrict__ out,
                                                   int doCopy) {
    const int bh = blockIdx.x;                 // b*HH + h
    const f4nat* row = (const f4nat*)(x + (size_t)bh * (WW * CC));
    f4nat* orow = (f4nat*)out + (size_t)bh * (WW * CC / 4);
    unsigned int* wrow = wmask + (size_t)bh * WW;
    const int t = threadIdx.x;
    unsigned int rowacc = 0;
    // 512*32 floats = 4096 f4; 256 threads -> 16 iters
    #pragma unroll 4
    for (int it = 0; it < 16; ++it) {
        int idx = it * 256 + t;                // f4 index; elements 4*idx..+3
        f4nat v = row[idx];
        if (doCopy) __builtin_nontemporal_store(v, orow + idx);
        unsigned int nib = (sig_bit(v.x) ? 1u : 0u) | (sig_bit(v.y) ? 2u : 0u) |
                           (sig_bit(v.z) ? 4u : 0u) | (sig_bit(v.w) ? 8u : 0u);
        // c = 4*(t&7)+e within this w; 8 consecutive lanes cover one w
        unsigned int m = nib << ((t & 7) * 4);
        m |= __shfl_xor(m, 1);
        m |= __shfl_xor(m, 2);
        m |= __shfl_xor(m, 4);                 // c-mask for w = idx>>3, uniform in 8-group
        rowacc |= m;
        if ((t & 7) == 0) wrow[idx >> 3] = m;
    }
    rowacc |= __shfl_xor(rowacc, 8);
    rowacc |= __shfl_xor(rowacc, 16);
    rowacc |= __shfl_xor(rowacc, 32);
    __shared__ unsigned int s[4];
    if ((t & 63) == 0) s[t >> 6] = rowacc;
    __syncthreads();
    if (t == 0) rowbits[bh] = s[0] | s[1] | s[2] | s[3];
}

// OR wmask over a 64-h chunk -> colpart[hchunk][b][w]. Plain stores.
__global__ __launch_bounds__(256) void colreduce_kernel(const unsigned int* __restrict__ wmask,
                                                        unsigned int* __restrict__ colpart) {
    const int blk = blockIdx.x;                // b(2b) | wchunk(1b) | hchunk(3b)
    const int b = blk >> 4;
    const int w = ((blk >> 3) & 1) * 256 + threadIdx.x;
    const int hk = blk & 7;
    const unsigned int* base = wmask + ((size_t)b * HH + hk * 64) * WW + w;
    unsigned int acc = 0;
    #pragma unroll 8
    for (int h = 0; h < 64; ++h) acc |= base[(size_t)h * WW];
    colpart[((size_t)hk * BB + b) * WW + w] = acc;
}

// One block per b. Stages colpart+rowbits through LDS (4 global loads per
// thread), reduces 8 h-chunks, then per-(c,32-lane) bbox scan + Params +
// per-b FastRec. Same arithmetic as the reference (incl. argmax quirks).
__global__ __launch_bounds__(1024) void bboxfin_kernel(const unsigned int* __restrict__ rowbits,
                                                       const unsigned int* __restrict__ colpart,
                                                       Params* __restrict__ prm,
                                                       FastRec* __restrict__ fast) {
    const int b = blockIdx.x;
    const int t = threadIdx.x;
    __shared__ unsigned int cm8[8 * WW];       // 16 KiB
    __shared__ unsigned int colmask[WW];
    __shared__ unsigned int rowmask[HH];
    #pragma unroll
    for (int j = 0; j < 4; ++j) {
        int u = j * 1024 + t;                  // 0..4095 = hk*512 + w
        cm8[u] = colpart[(size_t)(u >> 9) * (BB * WW) + b * WW + (u & 511)];
    }
    if (t < HH) rowmask[t] = rowbits[b * HH + t];
    __syncthreads();
    if (t < WW) {
        unsigned int a = 0;
        #pragma unroll
        for (int k = 0; k < 8; ++k) a |= cm8[k * WW + t];
        colmask[t] = a;
    }
    __syncthreads();
    const int c = t >> 5, lane = t & 31;
    int fx = WW, lx = -1, fy = HH, ly = -1;
    for (int m = 0; m < WW / 32; ++m) {
        int w = m * 32 + lane;
        if ((colmask[w] >> c) & 1u) { fx = min(fx, w); lx = max(lx, w); }
        if ((rowmask[w] >> c) & 1u) { fy = min(fy, w); ly = max(ly, w); }
    }
    for (int off = 16; off; off >>= 1) {       // stays within the 32-lane group
        fx = min(fx, __shfl_xor(fx, off));
        lx = max(lx, __shfl_xor(lx, off));
        fy = min(fy, __shfl_xor(fy, off));
        ly = max(ly, __shfl_xor(ly, off));
    }
    __shared__ Params sp[CC];
    __shared__ int ok[CC];
    if (lane == 0) {
        // argmax quirks: no active -> 0; min-side first-active at last index -> 0.
        int xm = (fx <= WW - 2) ? fx : 0;
        int xM = (lx >= 0) ? lx : 0;
        int ym = (fy <= HH - 2) ? fy : 0;
        int yM = (ly >= 0) ? ly : 0;
        int hc = max(yM - ym, 1), wc = max(xM - xm, 1);
        int zh = max(HH - 2 * PADC, hc), zw = max(WW - 2 * PADC, wc);
        float scale = fminf((float)zh / (float)hc, (float)zw / (float)wc);
        int rh = (int)rintf(scale * (float)hc);   // round-half-even = jnp.round
        int rw = (int)rintf(scale * (float)wc);
        int pad_y = max(0, (HH - rh) / 2), crop_y = max(0, (rh - HH) / 2);
        int pad_x = max(0, (WW - rw) / 2), crop_x = max(0, (rw - WW) / 2);
        Params p;
        p.ym = ym; p.xm = xm; p.hc = hc; p.wc = wc; p.rh = rh; p.rw = rw;
        p.dy = pad_y - crop_y; p.dx = pad_x - crop_x;
        p.ry = (float)hc / (float)rh;
        p.rx = (float)wc / (float)rw;
        sp[c] = p;
    }
    __syncthreads();
    if (t < CC) {
        Params p = sp[t];
        const Params& p0 = sp[0];
        bool simple = (p.rh == p.hc) && (p.rw == p.wc);   // => scale ratio exactly 1
        bool same = (p.ym == p0.ym) && (p.xm == p0.xm) && (p.dy == p0.dy) &&
                    (p.dx == p0.dx) && (p.rh == p0.rh) && (p.rw == p0.rw);
        ok[t] = (simple && same) ? 1 : 0;
        prm[b * CC + t] = p;
    }
    __syncthreads();
    if (t == 0) {
        int all = 1;
        for (int k = 0; k < CC; ++k) all &= ok[k];
        Params p0 = sp[0];
        FastRec f;
        f.flag = all;
        f.iLo = p0.dy; f.iHi = p0.dy + p0.rh;
        f.jLo = p0.dx; f.jHi = p0.dx + p0.rw;
        f.dY = p0.ym - p0.dy; f.dX = p0.xm - p0.dx;
        f.pad = 0;
        fast[b] = f;
    }
}

// Corrects the speculative identity copy. Identity case (flag && zero shift
// && zero origin): only zero the invalid borders (tiny). Otherwise: fully
// rewrite batch b with the general bilinear path.
__global__ __launch_bounds__(256) void fixup_kernel(const float* __restrict__ x,
                                                    const Params* __restrict__ prm,
                                                    const FastRec* __restrict__ fast,
                                                    float* __restrict__ out) {
    const int blk = blockIdx.x;                // 1024 blocks; 256 per batch
    const int t = threadIdx.x;
    const int b = blk >> 8, loc = blk & 255;
    FastRec f = fast[b];
    bool ident = f.flag && f.dY == 0 && f.dX == 0 && f.iLo == 0 && f.jLo == 0;
    if (ident) {
        if (loc >= 32) return;                 // 8192 threads handle the border
        const int rowsZ = HH - f.iHi;          // full zero rows at the bottom
        const int W8 = (WW - f.jHi) * 8;       // f4 per row in right zero strip
        const int rowElems = rowsZ * (WW * CC / 4 / 1);   // rowsZ * 4096
        const int total = rowElems + f.iHi * W8;
        for (int u = loc * 256 + t; u < total; u += 8192) {
            size_t q;
            if (u < rowElems) {
                int i = f.iHi + (u >> 12);     // 4096 f4 per row
                int r = u & 4095;
                q = ((size_t)b << 21) | ((size_t)i << 12) | r;
            } else {
                int v = u - rowElems;
                int i = v / W8;
                int r = v - i * W8;
                int j = f.jHi + (r >> 3);
                q = ((size_t)b << 21) | ((size_t)i << 12) | ((size_t)j << 3) | (r & 7);
            }
            __builtin_nontemporal_store((f4nat)0.0f, (f4nat*)out + q);
        }
        return;
    }
    __shared__ Params sp[CC];
    {
        const int nw = CC * (int)(sizeof(Params) / 4);
        const int* src = (const int*)(prm + b * CC);
        int* dst = (int*)sp;
        for (int k = t; k < nw; k += 256) dst[k] = src[k];
    }
    __syncthreads();
    const float* base = x + (size_t)b * ((size_t)HH * WW * CC);
    for (int u = loc * 256 + t; u < HH * WW * CC / 4; u += 65536) {
        const int c0 = (u & 7) * 4;
        const int j = (u >> 3) & 511;
        const int i = u >> 12;
        f4nat r;
        #pragma unroll
        for (int k = 0; k < 4; ++k) {
            Params p = sp[c0 + k];
            int ri = i - p.dy, rj = j - p.dx;
            bool valid = (ri >= 0) && (ri < p.rh) && (rj >= 0) && (rj < p.rw);
            float sy = (float)ri * p.ry;
            float sx = (float)rj * p.rx;
            int y0 = min(max((int)floorf(sy), 0), p.hc - 1);
            int x0 = min(max((int)floorf(sx), 0), p.wc - 1);
            int y1 = min(y0 + 1, p.hc - 1);
            int x1 = min(x0 + 1, p.wc - 1);
            float wy = fminf(fmaxf(sy - (float)y0, 0.0f), 1.0f);
            float wx = fminf(fmaxf(sx - (float)x0, 0.0f), 1.0f);
            int Y0 = min(p.ym + y0, HH - 1);
            int Y1 = min(p.ym + y1, HH - 1);
            int X0 = min(p.xm + x0, WW - 1);
            int X1 = min(p.xm + x1, WW - 1);
            float v00 = base[((size_t)Y0 * WW + X0) * CC + c0 + k];
            float v01 = base[((size_t)Y0 * WW + X1) * CC + c0 + k];
            float v10 = base[((size_t)Y1 * WW + X0) * CC + c0 + k];
            float v11 = base[((size_t)Y1 * WW + X1) * CC + c0 + k];
            float top = v00 * (1.0f - wx) + v01 * wx;
            float bot = v10 * (1.0f - wx) + v11 * wx;
            float o = top * (1.0f - wy) + bot * wy;
            r[k] = valid ? o : 0.0f;
        }
        __builtin_nontemporal_store(r, (f4nat*)out + (((size_t)b << 21) + u));
    }
}

// Non-fused fallback (ws too small for wmask): full gather pass.
__global__ __launch_bounds__(256) void focus_kernel(const float* __restrict__ x,
                                                    const Params* __restrict__ prm,
                                                    const FastRec* __restrict__ fast,
                                                    float* __restrict__ out) {
    const int t = threadIdx.x;
    const size_t q = (size_t)blockIdx.x * 256 + t;   // f4 index
    const int c0 = (int)(q & 7) * 4;
    const int j = (int)((q >> 3) & 511);
    const int i = (int)((q >> 12) & 511);
    const int b = (int)(q >> 21);

    FastRec f = fast[b];
    if (f.flag) {
        f4nat v = (f4nat)0.0f;
        if (i >= f.iLo && i < f.iHi && j >= f.jLo && j < f.jHi) {
            const float* src = x + ((size_t)b * HH + (i + f.dY)) * ((size_t)WW * CC) +
                               (size_t)(j + f.dX) * CC + c0;
            v = *(const f4nat*)src;
        }
        __builtin_nontemporal_store(v, (f4nat*)out + q);
        return;
    }
    __shared__ Params sp[CC];
    {
        const int nw = CC * (int)(sizeof(Params) / 4);
        const int* src = (const int*)(prm + b * CC);
        int* dst = (int*)sp;
        for (int k = t; k < nw; k += 256) dst[k] = src[k];
    }
    __syncthreads();
    const float* base = x + (size_t)b * ((size_t)HH * WW * CC);
    f4nat r;
    #pragma unroll
    for (int k = 0; k < 4; ++k) {
        Params p = sp[c0 + k];
        int ri = i - p.dy, rj = j - p.dx;
        bool valid = (ri >= 0) && (ri < p.rh) && (rj >= 0) && (rj < p.rw);
        float sy = (float)ri * p.ry;
        float sx = (float)rj * p.rx;
        int y0 = min(max((int)floorf(sy), 0), p.hc - 1);
        int x0 = min(max((int)floorf(sx), 0), p.wc - 1);
        int y1 = min(y0 + 1, p.hc - 1);
        int x1 = min(x0 + 1, p.wc - 1);
        float wy = fminf(fmaxf(sy - (float)y0, 0.0f), 1.0f);
        float wx = fminf(fmaxf(sx - (float)x0, 0.0f), 1.0f);
        int Y0 = min(p.ym + y0, HH - 1);
        int Y1 = min(p.ym + y1, HH - 1);
        int X0 = min(p.xm + x0, WW - 1);
        int X1 = min(p.xm + x1, WW - 1);
        float v00 = base[((size_t)Y0 * WW + X0) * CC + c0 + k];
        float v01 = base[((size_t)Y0 * WW + X1) * CC + c0 + k];
        float v10 = base[((size_t)Y1 * WW + X0) * CC + c0 + k];
        float v11 = base[((size_t)Y1 * WW + X1) * CC + c0 + k];
        float top = v00 * (1.0f - wx) + v01 * wx;
        float bot = v10 * (1.0f - wx) + v11 * wx;
        float o = top * (1.0f - wy) + bot * wy;
        r[k] = valid ? o : 0.0f;
    }
    __builtin_nontemporal_store(r, (f4nat*)out + q);
}

extern "C" void kernel_launch(void* const* d_in, const int* in_sizes, int n_in,
                              void* d_out, int out_size, void* d_ws, size_t ws_size,
                              hipStream_t stream) {
    const float* x = (const float*)d_in[0];
    float* out = (float*)d_out;
    unsigned char* ws = (unsigned char*)d_ws;
    unsigned int* colpart = (unsigned int*)ws;                 // 64 KiB
    unsigned int* rowbits = (unsigned int*)(ws + 65536);       // 8 KiB
    Params* prm = (Params*)(ws + 73728);                       // 5 KiB
    FastRec* fast = (FastRec*)(ws + 78848);                    // 128 B

    const size_t wmask_off = 81920;
    const size_t wmask_bytes = (size_t)BB * HH * WW * 4;       // 4 MiB
    const bool fused = ws_size >= wmask_off + wmask_bytes;
    unsigned int* wmask = fused ? (unsigned int*)(ws + wmask_off)
                                : (unsigned int*)d_out;        // scratch; focus overwrites

    hipLaunchKernelGGL(scan_kernel, dim3(BB * HH), dim3(256), 0, stream,
                       x, rowbits, wmask, out, fused ? 1 : 0);
    hipLaunchKernelGGL(colreduce_kernel, dim3(BB * 2 * 8), dim3(256), 0, stream,
                       wmask, colpart);
    hipLaunchKernelGGL(bboxfin_kernel, dim3(BB), dim3(1024), 0, stream,
                       rowbits, colpart, prm, fast);
    if (fused) {
        hipLaunchKernelGGL(fixup_kernel, dim3(1024), dim3(256), 0, stream,
                           x, prm, fast, out);
    } else {
        hipLaunchKernelGGL(focus_kernel, dim3((BB * HH * WW * CC / 4) / 256), dim3(256), 0, stream,
                           x, prm, fast, out);
    }
}

// Round 7
// 52.715 us; speedup vs baseline: 15.0949x; 1.0931x over previous
//
#include <hip/hip_runtime.h>
#include <math.h>

#define BB 4
#define HH 512
#define WW 512
#define CC 32
#define PADC 3
#define NHK 16   // h chunks of 32 rows
#define NWK 16   // w chunks of 32 cols

typedef float f4nat __attribute__((ext_vector_type(4)));  // NT-store-compatible

struct Params {
    int ym, xm, hc, wc, rh, rw, dy, dx;
    float ry, rx;
};

struct FastRec {
    int flag, iLo, iHi, jLo, jHi, dY, dX, pad;
};

// bit = round(sigmoid(v))==1. sigmoid monotone, sigmoid(0)=0.5 (round-half-
// even -> 0), so bit <=> v > 0. (FP-boundary mismatch vs the reference needs
// an entire 512-elem scan column inside (0, 6e-8): prob ~2^-512.)
__device__ __forceinline__ unsigned int pos_bit(float v) { return v > 0.0f ? 1u : 0u; }

// Fused detect+copy. One block per (b,hk,wk) tile: 32 rows x 32 w x 32 c.
// Streams the tile verbatim to out (speculative identity copy, corrected by
// fixup_kernel), assembles per-w channel masks via 8-lane shuffle-OR,
// ORs over rows in registers -> colpart; per-row wave OR + LDS -> rowpart.
__global__ __launch_bounds__(256) void scan_kernel(const float* __restrict__ x,
                                                   unsigned int* __restrict__ rowpart,
                                                   unsigned int* __restrict__ colpart,
                                                   float* __restrict__ out) {
    const int blk = blockIdx.x;                 // b(2) | hk(4) | wk(4)
    const int b = blk >> 8;
    const int hk = (blk >> 4) & 15;
    const int wk = blk & 15;
    const int t = threadIdx.x;
    const int c4 = t & 7;                       // f4 index within the 32 channels
    const int wi = t >> 3;                      // 0..31 within the 32-w tile

    __shared__ unsigned int rowbuf[32][4];      // [row][wave]

    // f4 index of (b, hk*32, wk*32 + wi, c4*4)
    size_t f0 = ((size_t)(b * HH + hk * 32) * WW + wk * 32 + wi) * (CC / 4) + c4;
    const f4nat* xin = (const f4nat*)x;
    f4nat* xout = (f4nat*)out;

    unsigned int colacc = 0;
    #pragma unroll 4
    for (int r = 0; r < 32; ++r) {
        size_t idx = f0 + (size_t)r * (WW * CC / 4);
        f4nat v = xin[idx];
        __builtin_nontemporal_store(v, xout + idx);
        unsigned int nib = pos_bit(v.x) | (pos_bit(v.y) << 1) |
                           (pos_bit(v.z) << 2) | (pos_bit(v.w) << 3);
        unsigned int m = nib << (c4 * 4);
        m |= __shfl_xor(m, 1);
        m |= __shfl_xor(m, 2);
        m |= __shfl_xor(m, 4);                  // full 32-c mask for this w, uniform in 8-group
        colacc |= m;
        unsigned int rm = m;
        rm |= __shfl_xor(rm, 8);
        rm |= __shfl_xor(rm, 16);
        rm |= __shfl_xor(rm, 32);               // OR over the wave's 8 w
        if ((t & 63) == 0) rowbuf[r][t >> 6] = rm;
    }
    if (c4 == 0)                                // one writer per w
        colpart[(size_t)(hk * BB + b) * WW + wk * 32 + wi] = colacc;
    __syncthreads();
    if (t < 32) {
        unsigned int rw = rowbuf[t][0] | rowbuf[t][1] | rowbuf[t][2] | rowbuf[t][3];
        rowpart[(size_t)(wk * BB + b) * HH + hk * 32 + t] = rw;
    }
}

// One block per b. ORs the 16 col/row partial chunks into LDS masks, then
// per-(c,32-lane) bbox scan + Params + per-b FastRec. Same arithmetic as the
// reference (incl. argmax quirks).
__global__ __launch_bounds__(1024) void bboxfin_kernel(const unsigned int* __restrict__ rowpart,
                                                       const unsigned int* __restrict__ colpart,
                                                       Params* __restrict__ prm,
                                                       FastRec* __restrict__ fast) {
    const int b = blockIdx.x;
    const int t = threadIdx.x;
    __shared__ unsigned int colmask[WW];
    __shared__ unsigned int rowmask[HH];
    if (t < WW) {
        unsigned int a = 0;
        #pragma unroll
        for (int k = 0; k < NHK; ++k) a |= colpart[(size_t)(k * BB + b) * WW + t];
        colmask[t] = a;
    } else {
        const int h = t - WW;
        unsigned int a = 0;
        #pragma unroll
        for (int k = 0; k < NWK; ++k) a |= rowpart[(size_t)(k * BB + b) * HH + h];
        rowmask[h] = a;
    }
    __syncthreads();
    const int c = t >> 5, lane = t & 31;
    int fx = WW, lx = -1, fy = HH, ly = -1;
    for (int m = 0; m < WW / 32; ++m) {
        int w = m * 32 + lane;
        if ((colmask[w] >> c) & 1u) { fx = min(fx, w); lx = max(lx, w); }
        if ((rowmask[w] >> c) & 1u) { fy = min(fy, w); ly = max(ly, w); }
    }
    for (int off = 16; off; off >>= 1) {       // stays within the 32-lane group
        fx = min(fx, __shfl_xor(fx, off));
        lx = max(lx, __shfl_xor(lx, off));
        fy = min(fy, __shfl_xor(fy, off));
        ly = max(ly, __shfl_xor(ly, off));
    }
    __shared__ Params sp[CC];
    __shared__ int ok[CC];
    if (lane == 0) {
        // argmax quirks: no active -> 0; min-side first-active at last index -> 0.
        int xm = (fx <= WW - 2) ? fx : 0;
        int xM = (lx >= 0) ? lx : 0;
        int ym = (fy <= HH - 2) ? fy : 0;
        int yM = (ly >= 0) ? ly : 0;
        int hc = max(yM - ym, 1), wc = max(xM - xm, 1);
        int zh = max(HH - 2 * PADC, hc), zw = max(WW - 2 * PADC, wc);
        float scale = fminf((float)zh / (float)hc, (float)zw / (float)wc);
        int rh = (int)rintf(scale * (float)hc);   // round-half-even = jnp.round
        int rw = (int)rintf(scale * (float)wc);
        int pad_y = max(0, (HH - rh) / 2), crop_y = max(0, (rh - HH) / 2);
        int pad_x = max(0, (WW - rw) / 2), crop_x = max(0, (rw - WW) / 2);
        Params p;
        p.ym = ym; p.xm = xm; p.hc = hc; p.wc = wc; p.rh = rh; p.rw = rw;
        p.dy = pad_y - crop_y; p.dx = pad_x - crop_x;
        p.ry = (float)hc / (float)rh;
        p.rx = (float)wc / (float)rw;
        sp[c] = p;
    }
    __syncthreads();
    if (t < CC) {
        Params p = sp[t];
        const Params& p0 = sp[0];
        bool simple = (p.rh == p.hc) && (p.rw == p.wc);   // => scale ratio exactly 1
        bool same = (p.ym == p0.ym) && (p.xm == p0.xm) && (p.dy == p0.dy) &&
                    (p.dx == p0.dx) && (p.rh == p0.rh) && (p.rw == p0.rw);
        ok[t] = (simple && same) ? 1 : 0;
        prm[b * CC + t] = p;
    }
    __syncthreads();
    if (t == 0) {
        int all = 1;
        for (int k = 0; k < CC; ++k) all &= ok[k];
        Params p0 = sp[0];
        FastRec f;
        f.flag = all;
        f.iLo = p0.dy; f.iHi = p0.dy + p0.rh;
        f.jLo = p0.dx; f.jHi = p0.dx + p0.rw;
        f.dY = p0.ym - p0.dy; f.dX = p0.xm - p0.dx;
        f.pad = 0;
        fast[b] = f;
    }
}

// Corrects the speculative identity copy. Identity case (flag && zero shift
// && zero origin): only zero the invalid borders (tiny). Otherwise: fully
// rewrite batch b with the general bilinear path.
__global__ __launch_bounds__(256) void fixup_kernel(const float* __restrict__ x,
                                                    const Params* __restrict__ prm,
                                                    const FastRec* __restrict__ fast,
                                                    float* __restrict__ out) {
    const int blk = blockIdx.x;                // 1024 blocks; 256 per batch
    const int t = threadIdx.x;
    const int b = blk >> 8, loc = blk & 255;
    FastRec f = fast[b];
    bool ident = f.flag && f.dY == 0 && f.dX == 0 && f.iLo == 0 && f.jLo == 0;
    if (ident) {
        if (loc >= 32) return;                 // 8192 threads handle the border
        const int rowsZ = HH - f.iHi;          // full zero rows at the bottom
        const int W8 = (WW - f.jHi) * 8;       // f4 per row in right zero strip
        const int rowElems = rowsZ * (WW * CC / 4);      // rowsZ * 4096
        const int total = rowElems + f.iHi * W8;
        for (int u = loc * 256 + t; u < total; u += 8192) {
            size_t q;
            if (u < rowElems) {
                int i = f.iHi + (u >> 12);     // 4096 f4 per row
                int r = u & 4095;
                q = ((size_t)b << 21) | ((size_t)i << 12) | r;
            } else {
                int v = u - rowElems;
                int i = v / W8;
                int r = v - i * W8;
                int j = f.jHi + (r >> 3);
                q = ((size_t)b << 21) | ((size_t)i << 12) | ((size_t)j << 3) | (r & 7);
            }
            __builtin_nontemporal_store((f4nat)0.0f, (f4nat*)out + q);
        }
        return;
    }
    __shared__ Params sp[CC];
    {
        const int nw = CC * (int)(sizeof(Params) / 4);
        const int* src = (const int*)(prm + b * CC);
        int* dst = (int*)sp;
        for (int k = t; k < nw; k += 256) dst[k] = src[k];
    }
    __syncthreads();
    const float* base = x + (size_t)b * ((size_t)HH * WW * CC);
    for (int u = loc * 256 + t; u < HH * WW * CC / 4; u += 65536) {
        const int c0 = (u & 7) * 4;
        const int j = (u >> 3) & 511;
        const int i = u >> 12;
        f4nat r;
        #pragma unroll
        for (int k = 0; k < 4; ++k) {
            Params p = sp[c0 + k];
            int ri = i - p.dy, rj = j - p.dx;
            bool valid = (ri >= 0) && (ri < p.rh) && (rj >= 0) && (rj < p.rw);
            float sy = (float)ri * p.ry;
            float sx = (float)rj * p.rx;
            int y0 = min(max((int)floorf(sy), 0), p.hc - 1);
            int x0 = min(max((int)floorf(sx), 0), p.wc - 1);
            int y1 = min(y0 + 1, p.hc - 1);
            int x1 = min(x0 + 1, p.wc - 1);
            float wy = fminf(fmaxf(sy - (float)y0, 0.0f), 1.0f);
            float wx = fminf(fmaxf(sx - (float)x0, 0.0f), 1.0f);
            int Y0 = min(p.ym + y0, HH - 1);
            int Y1 = min(p.ym + y1, HH - 1);
            int X0 = min(p.xm + x0, WW - 1);
            int X1 = min(p.xm + x1, WW - 1);
            float v00 = base[((size_t)Y0 * WW + X0) * CC + c0 + k];
            float v01 = base[((size_t)Y0 * WW + X1) * CC + c0 + k];
            float v10 = base[((size_t)Y1 * WW + X0) * CC + c0 + k];
            float v11 = base[((size_t)Y1 * WW + X1) * CC + c0 + k];
            float top = v00 * (1.0f - wx) + v01 * wx;
            float bot = v10 * (1.0f - wx) + v11 * wx;
            float o = top * (1.0f - wy) + bot * wy;
            r[k] = valid ? o : 0.0f;
        }
        __builtin_nontemporal_store(r, (f4nat*)out + (((size_t)b << 21) + u));
    }
}

extern "C" void kernel_launch(void* const* d_in, const int* in_sizes, int n_in,
                              void* d_out, int out_size, void* d_ws, size_t ws_size,
                              hipStream_t stream) {
    const float* x = (const float*)d_in[0];
    float* out = (float*)d_out;
    unsigned char* ws = (unsigned char*)d_ws;
    // ws layout (ws_size proven >= 4.3 MB in earlier rounds; we need 262 KB)
    unsigned int* colpart = (unsigned int*)ws;                 // NHK*BB*WW = 128 KiB
    unsigned int* rowpart = (unsigned int*)(ws + 131072);      // NWK*BB*HH = 128 KiB
    Params* prm = (Params*)(ws + 262144);                      // 5 KiB
    FastRec* fast = (FastRec*)(ws + 267264);                   // 128 B

    hipLaunchKernelGGL(scan_kernel, dim3(BB * NHK * NWK), dim3(256), 0, stream,
                       x, rowpart, colpart, out);
    hipLaunchKernelGGL(bboxfin_kernel, dim3(BB), dim3(1024), 0, stream,
                       rowpart, colpart, prm, fast);
    hipLaunchKernelGGL(fixup_kernel, dim3(1024), dim3(256), 0, stream,
                       x, prm, fast, out);
}